// Round 9
// baseline (471.836 us; speedup 1.0000x reference)
//
#include <hip/hip_runtime.h>
#include <hip/hip_bf16.h>

#define DEV __device__ __forceinline__

typedef __bf16 bf16x8 __attribute__((ext_vector_type(8)));
typedef float f32x4 __attribute__((ext_vector_type(4)));

DEV float ldflex(const void* p, long i, int bf) {
    return bf ? __bfloat162float(((const __hip_bfloat16*)p)[i]) : ((const float*)p)[i];
}
DEV bf16x8 ldfrag(const __hip_bfloat16* p) { return *(const bf16x8*)(const void*)p; }
DEV bf16x8 ldsfrag(const unsigned short* p) { return *(const bf16x8*)(const void*)p; }

// ---------------- dtype probe ----------------
__global__ void detect_dtype(const void* probe, int* flag) {
    if (blockIdx.x == 0 && threadIdx.x == 0) {
        const unsigned short* u = (const unsigned short*)probe;
        int sane = 0;
        for (int i = 0; i < 256; ++i) {
            unsigned short v = u[i];
            int e = (v >> 7) & 0xFF;
            if (v == 0 || (e >= 107 && e <= 147)) sane++;
        }
        *flag = (sane >= 192) ? 1 : 0;   // 1 = bf16 storage
    }
}

// ---------------- weight conversion into MFMA B-fragment order ----------------
struct CvtDesc { const void* src; int n; int off; int cin; int cout; };
struct CvtArgs { CvtDesc d[30]; };

__global__ void cvt_weights(CvtArgs a, __hip_bfloat16* __restrict__ wf,
                            float* __restrict__ bn, const int* __restrict__ flagp) {
    CvtDesc de = a.d[blockIdx.y];
    int i = blockIdx.x * 256 + threadIdx.x;
    if (i >= de.n) return;
    float v = ldflex(de.src, i, *flagp);
    if (de.cin == 0) { bn[de.off + i] = v; return; }
    int cin = de.cin;
    int KB = cin >> 5, NH = de.cout >> 4;
    int co = i / (cin * 27);
    int rem = i % (cin * 27);
    int ci = rem / 27, tap = rem % 27;
    int kb = ci >> 5, q = (ci >> 3) & 3, j = ci & 7;
    int half = co >> 4, n = co & 15, lane = q * 16 + n;
    (void)KB;
    wf[de.off + ((((tap * KB + kb) * NH + half) << 9) + lane * 8 + j)] = __float2bfloat16(v);
}

// ---------------- point lists ----------------
__global__ void build_lists(const int* __restrict__ p2v, int* __restrict__ cnt,
                            int* __restrict__ mini, int* __restrict__ list, int n) {
    int i = blockIdx.x * blockDim.x + threadIdx.x;
    if (i >= n) return;
    int v = p2v[i];
    int slot = atomicAdd(&cnt[v], 1);
    if (slot < 20) list[v * 20 + slot] = i;
    atomicMin(&mini[v], i);
}

__global__ void scatter_idx(const int* __restrict__ coors, int* __restrict__ idxmap) {
    int v = blockIdx.x * blockDim.x + threadIdx.x;
    if (v >= 40000) return;
    int x = coors[v * 4 + 1], y = coors[v * 4 + 2], z = coors[v * 4 + 3];
    idxmap[((size_t)z * 256 + y) * 256 + x] = v;
}

// ---------------- VFE: 4 threads per voxel (8 channels each), deterministic ----------
__global__ __launch_bounds__(256) void vfe_kernel(
    const void* __restrict__ points, const void* __restrict__ voxels,
    const void* __restrict__ w_in, const void* __restrict__ s_in, const void* __restrict__ t_in,
    const int* __restrict__ cnt, const int* __restrict__ mini, const int* __restrict__ list,
    __hip_bfloat16* __restrict__ hbuf, const int* __restrict__ flagp) {
    const int V = 40000, S = 20, N = 200000;
    int t = blockIdx.x * blockDim.x + threadIdx.x;
    if (t >= V * 4) return;
    int v = t >> 2, g = t & 3;           // g: channel group, channels [g*8, g*8+8)
    int bf = *flagp;
    float vx0 = ldflex(voxels, v * 4 + 0, bf);
    float vx1 = ldflex(voxels, v * 4 + 1, bf);
    float vx2 = ldflex(voxels, v * 4 + 2, bf);
    float vx3 = ldflex(voxels, v * 4 + 3, bf);
    int c_ = min(cnt[v], S);
    // ascending point order == reference stable-argsort order (determinism, R7 lesson)
    int idxs[20];
    for (int k = 0; k < c_; ++k) idxs[k] = list[v * S + k];
    for (int i = 1; i < c_; ++i) {
        int key = idxs[i]; int j = i - 1;
        while (j >= 0 && idxs[j] > key) { idxs[j + 1] = idxs[j]; --j; }
        idxs[j + 1] = key;
    }
    float acc[8];
#pragma unroll
    for (int o = 0; o < 8; ++o) acc[o] = 0.f;

    for (int k = 0; k < c_; ++k) {
        int p = idxs[k];
        float p0 = ldflex(points, p, bf);
        float p1 = ldflex(points, N + p, bf);
        float p2 = ldflex(points, 2 * N + p, bf);
        float p3 = ldflex(points, 3 * N + p, bf);
        float f0 = vx0 - p0, f1 = vx1 - p1, f2 = vx2 - p2, f3 = vx3 - p3;
        float mult = (k == 0) ? (float)(S - c_ + 1) : 1.f;
#pragma unroll
        for (int o = 0; o < 8; ++o) {
            int oo = g * 8 + o;
            float d = f0 * ldflex(w_in, oo * 8 + 0, bf) + f1 * ldflex(w_in, oo * 8 + 1, bf) +
                      f2 * ldflex(w_in, oo * 8 + 2, bf) + f3 * ldflex(w_in, oo * 8 + 3, bf) +
                      p0 * ldflex(w_in, oo * 8 + 4, bf) + p1 * ldflex(w_in, oo * 8 + 5, bf) +
                      p2 * ldflex(w_in, oo * 8 + 6, bf) + p3 * ldflex(w_in, oo * 8 + 7, bf);
            float r = fmaxf(d * ldflex(s_in, oo, bf) + ldflex(t_in, oo, bf), 0.f);
            acc[o] += r * mult;
        }
    }
#pragma unroll
    for (int o = 0; o < 8; ++o)
        hbuf[(size_t)v * 32 + g * 8 + o] = __float2bfloat16(acc[o] * 0.05f);
}

// ---------------- occupancy pools ----------------
__global__ void pool_occ0(const int* __restrict__ idxmap, float* __restrict__ out) {
    int idx = blockIdx.x * blockDim.x + threadIdx.x;
    if (idx >= 8 * 128 * 128) return;
    int w = idx % 128; int r = idx / 128;
    int h = r % 128;   int d = r / 128;
    float m = 0.f;
    for (int kd = 0; kd < 3; ++kd) {
        int id = d * 2 + kd - 1;
        if (id < 0 || id >= 16) continue;
        for (int kh = 0; kh < 3; ++kh) {
            int ih = h * 2 + kh - 1;
            if (ih < 0 || ih >= 256) continue;
            for (int kw = 0; kw < 3; ++kw) {
                int iw = w * 2 + kw - 1;
                if (iw < 0 || iw >= 256) continue;
                if (idxmap[((size_t)id * 256 + ih) * 256 + iw] >= 0) m = 1.f;
            }
        }
    }
    out[idx] = m;
}

__global__ void pool_occ(const float* __restrict__ in, float* __restrict__ out,
                         int Di, int Hi, int Wi, int Do, int Ho, int Wo, int stride) {
    int idx = blockIdx.x * blockDim.x + threadIdx.x;
    int total = Do * Ho * Wo;
    if (idx >= total) return;
    int w = idx % Wo; int r = idx / Wo;
    int h = r % Ho;   int d = r / Ho;
    float m = 0.f;
    for (int kd = 0; kd < 3; ++kd) {
        int id = d * stride + kd - 1;
        if (id < 0 || id >= Di) continue;
        for (int kh = 0; kh < 3; ++kh) {
            int ih = h * stride + kh - 1;
            if (ih < 0 || ih >= Hi) continue;
            for (int kw = 0; kw < 3; ++kw) {
                int iw = w * stride + kw - 1;
                if (iw < 0 || iw >= Wi) continue;
                m = fmaxf(m, in[((size_t)id * Hi + ih) * Wi + iw]);
            }
        }
    }
    out[idx] = m;
}

// ---------------- conv0: sparse gather implicit-GEMM MFMA, LDS-staged weights ---------
__global__ __launch_bounds__(256) void conv0_mfma(
    const __hip_bfloat16* __restrict__ hb, const int* __restrict__ idxmap,
    __hip_bfloat16* __restrict__ out,                 // padded (10,130,130,32)
    const __hip_bfloat16* __restrict__ wf, const float* __restrict__ bns,
    const float* __restrict__ occ) {
    __shared__ __align__(16) unsigned short smem[54 * 512];   // 54 frags = 55 KB
    for (int c = threadIdx.x; c < 54 * 64; c += 256) {
        int f = c >> 6, e = c & 63;
        *(bf16x8*)(smem + f * 512 + e * 8) = ldfrag(wf + ((size_t)f << 9) + e * 8);
    }
    __syncthreads();

    int wave = blockIdx.x * 4 + (threadIdx.x >> 6);  // 8192 spatial tiles
    int lane = threadIdx.x & 63;
    int tw = wave & 7; int r = wave >> 3;
    int h = r & 127;   int d = r >> 7;
    int w0 = tw * 16;
    int q = lane >> 4, n = lane & 15;

    f32x4 acc0 = {0.f, 0.f, 0.f, 0.f}, acc1 = {0.f, 0.f, 0.f, 0.f};
    const float* op = occ + ((size_t)(d * 128 + h)) * 128 + w0;
    float ocn = op[n];
    if (__ballot(ocn != 0.f)) {
#pragma unroll
        for (int kd = 0; kd < 3; ++kd) {
            int id = d * 2 + kd - 1;
            if (id < 0) continue;
#pragma unroll
            for (int kh = 0; kh < 3; ++kh) {
                int ih = h * 2 + kh - 1;
                if (ih < 0) continue;
                const int* ip = idxmap + ((size_t)id * 256 + ih) * 256;
#pragma unroll
                for (int kw = 0; kw < 3; ++kw) {
                    int tap = (kd * 3 + kh) * 3 + kw;
                    int iw = (w0 + n) * 2 + kw - 1;
                    int v = (iw >= 0) ? ip[iw] : -1;
                    int vv = (v >= 0) ? v : 40000;              // row 40000 = zeros
                    bf16x8 A = ldfrag(hb + (size_t)vv * 32 + q * 8);
                    acc0 = __builtin_amdgcn_mfma_f32_16x16x32_bf16(
                        A, ldsfrag(smem + (tap * 2 + 0) * 512 + lane * 8), acc0, 0, 0, 0);
                    acc1 = __builtin_amdgcn_mfma_f32_16x16x32_bf16(
                        A, ldsfrag(smem + (tap * 2 + 1) * 512 + lane * 8), acc1, 0, 0, 0);
                }
            }
        }
    }
#pragma unroll
    for (int half = 0; half < 2; ++half) {
        int co = half * 16 + n;
        float s = bns[co], b = bns[32 + co];
        f32x4 a = half ? acc1 : acc0;
#pragma unroll
        for (int r2 = 0; r2 < 4; ++r2) {
            int mm = q * 4 + r2;
            float oc = op[mm];
            float vv = fmaxf(a[r2] * s + b, 0.f) * oc;
            out[((size_t)((d + 1) * 130 + (h + 1)) * 130 + (w0 + mm + 1)) * 32 + co] =
                __float2bfloat16(vv);
        }
    }
}

// ---------------- dense implicit-GEMM MFMA conv, LDS-staged weights ----------------
// grid = (tiles/4) * NG blocks; hg = blockIdx % NG (all 4 waves share one weight set).
template <int CIN, int COUT, int STRIDE, int NHP>
__global__ __launch_bounds__(256) void conv_mfma(
    const __hip_bfloat16* __restrict__ in, __hip_bfloat16* __restrict__ out,
    const __hip_bfloat16* __restrict__ wf, const float* __restrict__ bns,
    const float* __restrict__ occ,
    int Hp, int Wp, int Do, int Ho, int Wo, int OHp, int OWp) {
    constexpr int KB = CIN / 32, NH = COUT / 16, NG = NH / NHP;
    constexpr int NFRAG = 27 * KB * NHP;
    __shared__ __align__(16) unsigned short smem[NFRAG * 512];

    int bx = blockIdx.x;
    int hg = bx % NG;
    int tg = bx / NG;
    int lane = threadIdx.x & 63;

    for (int c = threadIdx.x; c < NFRAG * 64; c += 256) {
        int f = c >> 6, e = c & 63;
        int tkb = f / NHP, hl = f - tkb * NHP;
        int srcf = tkb * NH + hg * NHP + hl;
        *(bf16x8*)(smem + f * 512 + e * 8) = ldfrag(wf + ((size_t)srcf << 9) + e * 8);
    }
    __syncthreads();

    int wave = tg * 4 + (threadIdx.x >> 6);
    int tiles_w = Wo >> 4;
    int tw = wave % tiles_w; int r = wave / tiles_w;
    int h = r % Ho; int d = r / Ho;
    int w0 = tw * 16;
    int q = lane >> 4, n = lane & 15;

    f32x4 acc[NHP];
#pragma unroll
    for (int i = 0; i < NHP; ++i) acc[i] = (f32x4){0.f, 0.f, 0.f, 0.f};

    const float* op = occ + ((size_t)(d * Ho + h)) * Wo + w0;
    float ocn = op[n];
    if (__ballot(ocn != 0.f)) {
#pragma unroll
        for (int kd = 0; kd < 3; ++kd) {
#pragma unroll
            for (int kh = 0; kh < 3; ++kh) {
#pragma unroll
                for (int kw = 0; kw < 3; ++kw) {
                    int tap = (kd * 3 + kh) * 3 + kw;
                    const __hip_bfloat16* ip = in +
                        ((size_t)((d * STRIDE + kd) * Hp + (h * STRIDE + kh)) * Wp +
                         (w0 * STRIDE + kw)) * CIN;
#pragma unroll
                    for (int kb = 0; kb < KB; ++kb) {
                        bf16x8 A = ldfrag(ip + (n * STRIDE) * CIN + kb * 32 + q * 8);
#pragma unroll
                        for (int i = 0; i < NHP; ++i)
                            acc[i] = __builtin_amdgcn_mfma_f32_16x16x32_bf16(
                                A,
                                ldsfrag(smem + ((tap * KB + kb) * NHP + i) * 512 + lane * 8),
                                acc[i], 0, 0, 0);
                    }
                }
            }
        }
    }
#pragma unroll
    for (int i = 0; i < NHP; ++i) {
        int co = (hg * NHP + i) * 16 + n;
        float s = bns[co], b = bns[COUT + co];
#pragma unroll
        for (int r2 = 0; r2 < 4; ++r2) {
            int mm = q * 4 + r2;
            float oc = op[mm];
            float vv = fmaxf(acc[i][r2] * s + b, 0.f) * oc;
            out[((size_t)((d + 1) * OHp + (h + 1)) * OWp + (w0 + mm + 1)) * COUT + co] =
                __float2bfloat16(vv);
        }
    }
}

// ---------------- final conv 64->128, NCDHW typed output, LDS-staged weights ---------
__global__ __launch_bounds__(256) void conv_out_mfma(
    const __hip_bfloat16* __restrict__ in,            // padded (4,34,34,64)
    void* __restrict__ outv,
    const __hip_bfloat16* __restrict__ wf, const float* __restrict__ bns,
    const float* __restrict__ occ, const int* __restrict__ flagp) {
    constexpr int KB = 2, NH = 8;
    __shared__ __align__(16) unsigned short smem[27 * KB * 512];
    int bx = blockIdx.x;            // 256 blocks = 32 tile-groups × 8 halves
    int hg = bx & 7;
    int tg = bx >> 3;
    int lane = threadIdx.x & 63;

    for (int c = threadIdx.x; c < 27 * KB * 64; c += 256) {
        int f = c >> 6, e = c & 63;
        int srcf = f * NH + hg;     // f = tap*KB+kb
        *(bf16x8*)(smem + f * 512 + e * 8) = ldfrag(wf + ((size_t)srcf << 9) + e * 8);
    }
    __syncthreads();

    int wave = tg * 4 + (threadIdx.x >> 6);   // spatial tile 0..127
    int tw = wave & 1; int r = wave >> 1;
    int h = r & 31;    int d = r >> 5;
    int w0 = tw * 16;
    int q = lane >> 4, n = lane & 15;

    f32x4 acc = {0.f, 0.f, 0.f, 0.f};
    const float* op = occ + ((size_t)(d * 32 + h)) * 32 + w0;
    float ocn = op[n];
    if (__ballot(ocn != 0.f)) {
#pragma unroll
        for (int kd = 0; kd < 3; ++kd) {
#pragma unroll
            for (int kh = 0; kh < 3; ++kh) {
#pragma unroll
                for (int kw = 0; kw < 3; ++kw) {
                    int tap = (kd * 3 + kh) * 3 + kw;
                    const __hip_bfloat16* ip = in +
                        ((size_t)((d + kd) * 34 + (h + kh)) * 34 + (w0 + kw)) * 64;
#pragma unroll
                    for (int kb = 0; kb < KB; ++kb) {
                        bf16x8 A = ldfrag(ip + n * 64 + kb * 32 + q * 8);
                        acc = __builtin_amdgcn_mfma_f32_16x16x32_bf16(
                            A, ldsfrag(smem + (tap * KB + kb) * 512 + lane * 8),
                            acc, 0, 0, 0);
                    }
                }
            }
        }
    }
    int bf = *flagp;
    int co = hg * 16 + n;
    float s = bns[co], b = bns[128 + co];
#pragma unroll
    for (int r2 = 0; r2 < 4; ++r2) {
        int mm = q * 4 + r2;
        float oc = op[mm];
        float vv = fmaxf(acc[r2] * s + b, 0.f) * oc;
        size_t off = (size_t)co * 2048 + ((size_t)(d * 32 + h)) * 32 + (w0 + mm);
        if (bf) ((__hip_bfloat16*)outv)[off] = __float2bfloat16(vv);
        else    ((float*)outv)[off] = vv;
    }
}

// ---------------- launch ----------------
extern "C" void kernel_launch(void* const* d_in, const int* in_sizes, int n_in,
                              void* d_out, int out_size, void* d_ws, size_t ws_size,
                              hipStream_t stream) {
    const void* points = d_in[0];
    const void* voxels = d_in[1];
    const void* w_in   = d_in[2];
    const void* s_in   = d_in[3];
    const void* t_in   = d_in[4];
    const int* coors = (const int*)d_in[35];
    const int* p2v   = (const int*)d_in[36];

    char* ws = (char*)d_ws;
    __hip_bfloat16* wf   = (__hip_bfloat16*)(ws + 0);          // 912,384 bf16
    float*          bn   = (float*)(ws + 1835008);             // 1,216 f32
    __hip_bfloat16* hbuf = (__hip_bfloat16*)(ws + 4194304);    // 40001*32 bf16
    int*   idxmap = (int*)(ws + 8388608);                      // 4 MiB
    __hip_bfloat16* xP0A = (__hip_bfloat16*)(ws + 12582912);   // 10*130*130*32
    __hip_bfloat16* xP0B = (__hip_bfloat16*)(ws + 23398912);
    __hip_bfloat16* xP1A = (__hip_bfloat16*)(ws + 34214912);   // 6*66*66*64
    __hip_bfloat16* xP1B = (__hip_bfloat16*)(ws + 37560320);
    __hip_bfloat16* xP2A = (__hip_bfloat16*)(ws + 40905728);   // 4*34*34*64
    __hip_bfloat16* xP2B = (__hip_bfloat16*)(ws + 41497600);
    float* occ1 = (float*)(ws + 42089472);
    float* occ2 = (float*)(ws + 42613760);
    float* occ3 = (float*)(ws + 42679296);
    float* occ4 = (float*)(ws + 42687488);
    int*   cnt  = (int*)(ws + 42695680);
    int*   mini = (int*)(ws + 42855680);
    int*   list = (int*)(ws + 43015680);
    int*   flag = (int*)(ws + 46215680);

    (void)hipMemsetAsync(idxmap, 0xFF, 4194304, stream);
    (void)hipMemsetAsync(cnt, 0, 160000, stream);
    (void)hipMemsetAsync(mini, 0x7f, 160000, stream);
    (void)hipMemsetAsync(hbuf, 0, 2560064, stream);
    (void)hipMemsetAsync(xP0A, 0, 29506560, stream);   // all six activation buffers

    detect_dtype<<<1, 64, 0, stream>>>(points, flag);

    static const int widx[30] = {5,6,7, 8,9,10, 11,12,13, 14,15,16, 17,18,19,
                                 20,21,22, 23,24,25, 26,27,28, 29,30,31, 32,33,34};
    static const int wnn[30]  = {27648,32,32, 27648,32,32, 27648,32,32,
                                 55296,64,64, 110592,64,64, 110592,64,64,
                                 110592,64,64, 110592,64,64, 110592,64,64,
                                 221184,128,128};
    static const int woff[30] = {0,0,32, 27648,64,96, 55296,128,160,
                                 82944,192,256, 138240,320,384, 248832,448,512,
                                 359424,576,640, 470016,704,768, 580608,832,896,
                                 691200,960,1088};
    static const int wcin[30]  = {32,0,0, 32,0,0, 32,0,0, 32,0,0, 64,0,0,
                                  64,0,0, 64,0,0, 64,0,0, 64,0,0, 64,0,0};
    static const int wcout[30] = {32,0,0, 32,0,0, 32,0,0, 64,0,0, 64,0,0,
                                  64,0,0, 64,0,0, 64,0,0, 64,0,0, 128,0,0};
    CvtArgs ca;
    for (int i = 0; i < 30; ++i)
        ca.d[i] = CvtDesc{ d_in[widx[i]], wnn[i], woff[i], wcin[i], wcout[i] };
    cvt_weights<<<dim3(864, 30), 256, 0, stream>>>(ca, wf, bn, flag);

    build_lists<<<782, 256, 0, stream>>>(p2v, cnt, mini, list, 200000);
    scatter_idx<<<157, 256, 0, stream>>>(coors, idxmap);
    vfe_kernel<<<625, 256, 0, stream>>>(points, voxels, w_in, s_in, t_in,
                                        cnt, mini, list, hbuf, flag);

    // stage 0: -> (8,128,128) x32
    pool_occ0<<<512, 256, 0, stream>>>(idxmap, occ1);
    conv0_mfma<<<2048, 256, 0, stream>>>(hbuf, idxmap, xP0A, wf + 0, bn + 0, occ1);
    conv_mfma<32, 32, 1, 2><<<2048, 256, 0, stream>>>(
        xP0A, xP0B, wf + 27648, bn + 64, occ1, 130, 130, 8, 128, 128, 130, 130);
    conv_mfma<32, 32, 1, 2><<<2048, 256, 0, stream>>>(
        xP0B, xP0A, wf + 55296, bn + 128, occ1, 130, 130, 8, 128, 128, 130, 130);

    // stage 1: -> (4,64,64) x64   (256 tile-groups × 4 halves = 1024 blocks)
    pool_occ<<<64, 256, 0, stream>>>(occ1, occ2, 8, 128, 128, 4, 64, 64, 2);
    conv_mfma<32, 64, 2, 1><<<1024, 256, 0, stream>>>(
        xP0A, xP1A, wf + 82944, bn + 192, occ2, 130, 130, 4, 64, 64, 66, 66);
    conv_mfma<64, 64, 1, 1><<<1024, 256, 0, stream>>>(
        xP1A, xP1B, wf + 138240, bn + 320, occ2, 66, 66, 4, 64, 64, 66, 66);
    conv_mfma<64, 64, 1, 1><<<1024, 256, 0, stream>>>(
        xP1B, xP1A, wf + 248832, bn + 448, occ2, 66, 66, 4, 64, 64, 66, 66);

    // stage 2: -> (2,32,32) x64   (32 tile-groups × 4 halves = 128 blocks)
    pool_occ<<<8, 256, 0, stream>>>(occ2, occ3, 4, 64, 64, 2, 32, 32, 2);
    conv_mfma<64, 64, 2, 1><<<128, 256, 0, stream>>>(
        xP1A, xP2A, wf + 359424, bn + 576, occ3, 66, 66, 2, 32, 32, 34, 34);
    conv_mfma<64, 64, 1, 1><<<128, 256, 0, stream>>>(
        xP2A, xP2B, wf + 470016, bn + 704, occ3, 34, 34, 2, 32, 32, 34, 34);
    conv_mfma<64, 64, 1, 1><<<128, 256, 0, stream>>>(
        xP2B, xP2A, wf + 580608, bn + 832, occ3, 34, 34, 2, 32, 32, 34, 34);

    // final: -> (128,2,32,32)   (32 tile-groups × 8 halves = 256 blocks)
    pool_occ<<<8, 256, 0, stream>>>(occ3, occ4, 2, 32, 32, 2, 32, 32, 1);
    conv_out_mfma<<<256, 256, 0, stream>>>(xP2A, d_out, wf + 691200, bn + 960, occ4, flag);
}

// Round 10
// 423.098 us; speedup vs baseline: 1.1152x; 1.1152x over previous
//
#include <hip/hip_runtime.h>
#include <hip/hip_bf16.h>

#define DEV __device__ __forceinline__

typedef __bf16 bf16x8 __attribute__((ext_vector_type(8)));
typedef float f32x4 __attribute__((ext_vector_type(4)));

DEV float ldflex(const void* p, long i, int bf) {
    return bf ? __bfloat162float(((const __hip_bfloat16*)p)[i]) : ((const float*)p)[i];
}
DEV bf16x8 ldfrag(const __hip_bfloat16* p) { return *(const bf16x8*)(const void*)p; }

// ---------------- dtype probe ----------------
__global__ void detect_dtype(const void* probe, int* flag) {
    if (blockIdx.x == 0 && threadIdx.x == 0) {
        const unsigned short* u = (const unsigned short*)probe;
        int sane = 0;
        for (int i = 0; i < 256; ++i) {
            unsigned short v = u[i];
            int e = (v >> 7) & 0xFF;
            if (v == 0 || (e >= 107 && e <= 147)) sane++;
        }
        *flag = (sane >= 192) ? 1 : 0;   // 1 = bf16 storage
    }
}

// ---------------- weight conversion into MFMA B-fragment order ----------------
struct CvtDesc { const void* src; int n; int off; int cin; int cout; };
struct CvtArgs { CvtDesc d[30]; };

__global__ void cvt_weights(CvtArgs a, __hip_bfloat16* __restrict__ wf,
                            float* __restrict__ bn, const int* __restrict__ flagp) {
    CvtDesc de = a.d[blockIdx.y];
    int i = blockIdx.x * 256 + threadIdx.x;
    if (i >= de.n) return;
    float v = ldflex(de.src, i, *flagp);
    if (de.cin == 0) { bn[de.off + i] = v; return; }
    int cin = de.cin;
    int KB = cin >> 5, NH = de.cout >> 4;
    int co = i / (cin * 27);
    int rem = i % (cin * 27);
    int ci = rem / 27, tap = rem % 27;
    int kb = ci >> 5, q = (ci >> 3) & 3, j = ci & 7;
    int half = co >> 4, n = co & 15, lane = q * 16 + n;
    (void)KB;
    wf[de.off + ((((tap * KB + kb) * NH + half) << 9) + lane * 8 + j)] = __float2bfloat16(v);
}

// ---------------- point lists ----------------
__global__ void build_lists(const int* __restrict__ p2v, int* __restrict__ cnt,
                            int* __restrict__ list, int n) {
    int i = blockIdx.x * blockDim.x + threadIdx.x;
    if (i >= n) return;
    int v = p2v[i];
    int slot = atomicAdd(&cnt[v], 1);
    if (slot < 20) list[v * 20 + slot] = i;
}

// scatter voxel->grid index + assign deterministic slot ranks (sorted point order)
__global__ void scatter_rank(const int* __restrict__ coors, int* __restrict__ idxmap,
                             const int* __restrict__ cnt, const int* __restrict__ list,
                             int* __restrict__ slotbuf) {
    int v = blockIdx.x * blockDim.x + threadIdx.x;
    if (v >= 40000) return;
    int x = coors[v * 4 + 1], y = coors[v * 4 + 2], z = coors[v * 4 + 3];
    idxmap[((size_t)z * 256 + y) * 256 + x] = v;
    int c_ = min(cnt[v], 20);
    int idxs[20];
    for (int k = 0; k < c_; ++k) idxs[k] = list[v * 20 + k];
    for (int i = 1; i < c_; ++i) {
        int key = idxs[i]; int j = i - 1;
        while (j >= 0 && idxs[j] > key) { idxs[j + 1] = idxs[j]; --j; }
        idxs[j + 1] = key;
    }
    for (int k = 0; k < c_; ++k) slotbuf[idxs[k]] = k;   // rank in ascending-index order
}

// ---------------- VFE pass 1: point-major, coalesced reads, per-slot contributions ------
__global__ __launch_bounds__(256) void vfe_points(
    const void* __restrict__ points, const void* __restrict__ voxels,
    const void* __restrict__ w_in, const void* __restrict__ s_in, const void* __restrict__ t_in,
    const int* __restrict__ p2v, const int* __restrict__ cnt,
    const int* __restrict__ slotbuf, float* __restrict__ hbuf5,
    const int* __restrict__ flagp) {
    const int N = 200000, S = 20;
    __shared__ float lw[256], lsc[32], lbi[32];
    int bf = *flagp;
    if (threadIdx.x < 256) lw[threadIdx.x] = ldflex(w_in, threadIdx.x, bf);
    if (threadIdx.x < 32) {
        lsc[threadIdx.x] = ldflex(s_in, threadIdx.x, bf);
        lbi[threadIdx.x] = ldflex(t_in, threadIdx.x, bf);
    }
    __syncthreads();
    int i = blockIdx.x * 256 + threadIdx.x;
    if (i >= N) return;
    int slot = slotbuf[i];
    if (slot >= S) return;
    int v = p2v[i];
    float p0 = ldflex(points, i, bf);
    float p1 = ldflex(points, N + i, bf);
    float p2 = ldflex(points, 2 * N + i, bf);
    float p3 = ldflex(points, 3 * N + i, bf);
    float f0 = ldflex(voxels, v * 4 + 0, bf) - p0;
    float f1 = ldflex(voxels, v * 4 + 1, bf) - p1;
    float f2 = ldflex(voxels, v * 4 + 2, bf) - p2;
    float f3 = ldflex(voxels, v * 4 + 3, bf) - p3;
    int c_ = min(cnt[v], S);
    float mult = (slot == 0) ? (float)(S - c_ + 1) : 1.f;   // ref pads with first point
    float* out = hbuf5 + ((size_t)v * S + slot) * 32;
#pragma unroll
    for (int o = 0; o < 32; ++o) {
        float d = f0 * lw[o * 8 + 0] + f1 * lw[o * 8 + 1] + f2 * lw[o * 8 + 2] +
                  f3 * lw[o * 8 + 3] + p0 * lw[o * 8 + 4] + p1 * lw[o * 8 + 5] +
                  p2 * lw[o * 8 + 6] + p3 * lw[o * 8 + 7];
        out[o] = fmaxf(d * lsc[o] + lbi[o], 0.f) * mult;
    }
}

// ---------------- VFE pass 2: deterministic slot-order reduce -> bf16 h[v][32] ---------
__global__ __launch_bounds__(256) void vfe_reduce(
    const float* __restrict__ hbuf5, const int* __restrict__ cnt,
    __hip_bfloat16* __restrict__ hbuf) {
    int t = blockIdx.x * 256 + threadIdx.x;
    if (t >= 160000) return;
    int v = t >> 2, g = t & 3;
    int c_ = min(cnt[v], 20);
    f32x4 s0 = {0, 0, 0, 0}, s1 = {0, 0, 0, 0};
    const float* base = hbuf5 + (size_t)v * 20 * 32 + g * 8;
    for (int s = 0; s < c_; ++s) {          // ascending slot = ascending point index
        const f32x4* p = (const f32x4*)(base + s * 32);
        s0 += p[0]; s1 += p[1];
    }
    __hip_bfloat16* o = hbuf + (size_t)v * 32 + g * 8;
#pragma unroll
    for (int j = 0; j < 4; ++j) {
        o[j] = __float2bfloat16(s0[j] * 0.05f);
        o[4 + j] = __float2bfloat16(s1[j] * 0.05f);
    }
}

// ---------------- occupancy pools ----------------
__global__ void pool_occ0(const int* __restrict__ idxmap, float* __restrict__ out) {
    int idx = blockIdx.x * blockDim.x + threadIdx.x;
    if (idx >= 8 * 128 * 128) return;
    int w = idx % 128; int r = idx / 128;
    int h = r % 128;   int d = r / 128;
    float m = 0.f;
    for (int kd = 0; kd < 3; ++kd) {
        int id = d * 2 + kd - 1;
        if (id < 0 || id >= 16) continue;
        for (int kh = 0; kh < 3; ++kh) {
            int ih = h * 2 + kh - 1;
            if (ih < 0 || ih >= 256) continue;
            for (int kw = 0; kw < 3; ++kw) {
                int iw = w * 2 + kw - 1;
                if (iw < 0 || iw >= 256) continue;
                if (idxmap[((size_t)id * 256 + ih) * 256 + iw] >= 0) m = 1.f;
            }
        }
    }
    out[idx] = m;
}

__global__ void pool_occ(const float* __restrict__ in, float* __restrict__ out,
                         int Di, int Hi, int Wi, int Do, int Ho, int Wo, int stride) {
    int idx = blockIdx.x * blockDim.x + threadIdx.x;
    int total = Do * Ho * Wo;
    if (idx >= total) return;
    int w = idx % Wo; int r = idx / Wo;
    int h = r % Ho;   int d = r / Ho;
    float m = 0.f;
    for (int kd = 0; kd < 3; ++kd) {
        int id = d * stride + kd - 1;
        if (id < 0 || id >= Di) continue;
        for (int kh = 0; kh < 3; ++kh) {
            int ih = h * stride + kh - 1;
            if (ih < 0 || ih >= Hi) continue;
            for (int kw = 0; kw < 3; ++kw) {
                int iw = w * stride + kw - 1;
                if (iw < 0 || iw >= Wi) continue;
                m = fmaxf(m, in[((size_t)id * Hi + ih) * Wi + iw]);
            }
        }
    }
    out[idx] = m;
}

// ---------------- conv0: sparse gather implicit-GEMM MFMA (R8 version) ----------------
__global__ __launch_bounds__(256) void conv0_mfma(
    const __hip_bfloat16* __restrict__ hb, const int* __restrict__ idxmap,
    __hip_bfloat16* __restrict__ out,                 // padded (10,130,130,32)
    const __hip_bfloat16* __restrict__ wf, const float* __restrict__ bns,
    const float* __restrict__ occ) {
    int wave = (blockIdx.x * 256 + threadIdx.x) >> 6;  // 8192 waves
    int lane = threadIdx.x & 63;
    int tw = wave & 7; int r = wave >> 3;
    int h = r & 127;   int d = r >> 7;
    int w0 = tw * 16;
    int q = lane >> 4, n = lane & 15;

    f32x4 acc0 = {0.f, 0.f, 0.f, 0.f}, acc1 = {0.f, 0.f, 0.f, 0.f};
    const float* op = occ + ((size_t)(d * 128 + h)) * 128 + w0;
    float ocn = op[n];
    if (__ballot(ocn != 0.f)) {
#pragma unroll
        for (int kd = 0; kd < 3; ++kd) {
            int id = d * 2 + kd - 1;
            if (id < 0) continue;
#pragma unroll
            for (int kh = 0; kh < 3; ++kh) {
                int ih = h * 2 + kh - 1;
                if (ih < 0) continue;
                const int* ip = idxmap + ((size_t)id * 256 + ih) * 256;
#pragma unroll
                for (int kw = 0; kw < 3; ++kw) {
                    int tap = (kd * 3 + kh) * 3 + kw;
                    int iw = (w0 + n) * 2 + kw - 1;
                    int v = (iw >= 0) ? ip[iw] : -1;
                    int vv = (v >= 0) ? v : 40000;              // row 40000 = zeros
                    bf16x8 A = ldfrag(hb + (size_t)vv * 32 + q * 8);
                    acc0 = __builtin_amdgcn_mfma_f32_16x16x32_bf16(
                        A, ldfrag(wf + ((tap * 2 + 0) << 9) + lane * 8), acc0, 0, 0, 0);
                    acc1 = __builtin_amdgcn_mfma_f32_16x16x32_bf16(
                        A, ldfrag(wf + ((tap * 2 + 1) << 9) + lane * 8), acc1, 0, 0, 0);
                }
            }
        }
    }
#pragma unroll
    for (int half = 0; half < 2; ++half) {
        int co = half * 16 + n;
        float s = bns[co], b = bns[32 + co];
        f32x4 a = half ? acc1 : acc0;
#pragma unroll
        for (int r2 = 0; r2 < 4; ++r2) {
            int mm = q * 4 + r2;
            float oc = op[mm];
            float vv = fmaxf(a[r2] * s + b, 0.f) * oc;
            out[((size_t)((d + 1) * 130 + (h + 1)) * 130 + (w0 + mm + 1)) * 32 + co] =
                __float2bfloat16(vv);
        }
    }
}

// ---------------- dense implicit-GEMM MFMA conv (R8 version) ----------------
template <int CIN, int COUT, int STRIDE, int NHP>
__global__ __launch_bounds__(256) void conv_mfma(
    const __hip_bfloat16* __restrict__ in, __hip_bfloat16* __restrict__ out,
    const __hip_bfloat16* __restrict__ wf, const float* __restrict__ bns,
    const float* __restrict__ occ,
    int Hp, int Wp, int Do, int Ho, int Wo, int OHp, int OWp) {
    constexpr int KB = CIN / 32, NH = COUT / 16, NG = NH / NHP;
    int gw = (blockIdx.x * 256 + threadIdx.x) >> 6;
    int lane = threadIdx.x & 63;
    int hg = gw & (NG - 1);
    int wave = gw / NG;
    int tiles_w = Wo >> 4;
    int tw = wave % tiles_w; int r = wave / tiles_w;
    int h = r % Ho; int d = r / Ho;
    int w0 = tw * 16;
    int q = lane >> 4, n = lane & 15;

    f32x4 acc[NHP];
#pragma unroll
    for (int i = 0; i < NHP; ++i) acc[i] = (f32x4){0.f, 0.f, 0.f, 0.f};

    const float* op = occ + ((size_t)(d * Ho + h)) * Wo + w0;
    float ocn = op[n];
    if (__ballot(ocn != 0.f)) {
#pragma unroll
        for (int kd = 0; kd < 3; ++kd) {
#pragma unroll
            for (int kh = 0; kh < 3; ++kh) {
#pragma unroll
                for (int kw = 0; kw < 3; ++kw) {
                    int tap = (kd * 3 + kh) * 3 + kw;
                    const __hip_bfloat16* ip = in +
                        ((size_t)((d * STRIDE + kd) * Hp + (h * STRIDE + kh)) * Wp +
                         (w0 * STRIDE + kw)) * CIN;
#pragma unroll
                    for (int kb = 0; kb < KB; ++kb) {
                        bf16x8 A = ldfrag(ip + (n * STRIDE) * CIN + kb * 32 + q * 8);
#pragma unroll
                        for (int i = 0; i < NHP; ++i) {
                            int half = hg * NHP + i;
                            acc[i] = __builtin_amdgcn_mfma_f32_16x16x32_bf16(
                                A,
                                ldfrag(wf + (((tap * KB + kb) * NH + half) << 9) + lane * 8),
                                acc[i], 0, 0, 0);
                        }
                    }
                }
            }
        }
    }
#pragma unroll
    for (int i = 0; i < NHP; ++i) {
        int co = (hg * NHP + i) * 16 + n;
        float s = bns[co], b = bns[COUT + co];
#pragma unroll
        for (int r2 = 0; r2 < 4; ++r2) {
            int mm = q * 4 + r2;
            float oc = op[mm];
            float vv = fmaxf(acc[i][r2] * s + b, 0.f) * oc;
            out[((size_t)((d + 1) * OHp + (h + 1)) * OWp + (w0 + mm + 1)) * COUT + co] =
                __float2bfloat16(vv);
        }
    }
}

// ---------------- final conv 64->128, NCDHW typed output (R8 version) ----------------
__global__ __launch_bounds__(256) void conv_out_mfma(
    const __hip_bfloat16* __restrict__ in,            // padded (4,34,34,64)
    void* __restrict__ outv,
    const __hip_bfloat16* __restrict__ wf, const float* __restrict__ bns,
    const float* __restrict__ occ, const int* __restrict__ flagp) {
    constexpr int KB = 2, NH = 8;
    int gw = (blockIdx.x * 256 + threadIdx.x) >> 6;   // 1024 waves
    int lane = threadIdx.x & 63;
    int hg = gw & 7;
    int wave = gw >> 3;
    int tw = wave & 1; int r = wave >> 1;
    int h = r & 31;    int d = r >> 5;
    int w0 = tw * 16;
    int q = lane >> 4, n = lane & 15;

    f32x4 acc = {0.f, 0.f, 0.f, 0.f};
    const float* op = occ + ((size_t)(d * 32 + h)) * 32 + w0;
    float ocn = op[n];
    if (__ballot(ocn != 0.f)) {
#pragma unroll
        for (int kd = 0; kd < 3; ++kd) {
#pragma unroll
            for (int kh = 0; kh < 3; ++kh) {
#pragma unroll
                for (int kw = 0; kw < 3; ++kw) {
                    int tap = (kd * 3 + kh) * 3 + kw;
                    const __hip_bfloat16* ip = in +
                        ((size_t)((d + kd) * 34 + (h + kh)) * 34 + (w0 + kw)) * 64;
#pragma unroll
                    for (int kb = 0; kb < KB; ++kb) {
                        bf16x8 A = ldfrag(ip + n * 64 + kb * 32 + q * 8);
                        acc = __builtin_amdgcn_mfma_f32_16x16x32_bf16(
                            A, ldfrag(wf + (((tap * KB + kb) * NH + hg) << 9) + lane * 8),
                            acc, 0, 0, 0);
                    }
                }
            }
        }
    }
    int bf = *flagp;
    int co = hg * 16 + n;
    float s = bns[co], b = bns[128 + co];
#pragma unroll
    for (int r2 = 0; r2 < 4; ++r2) {
        int mm = q * 4 + r2;
        float oc = op[mm];
        float vv = fmaxf(acc[r2] * s + b, 0.f) * oc;
        size_t off = (size_t)co * 2048 + ((size_t)(d * 32 + h)) * 32 + (w0 + mm);
        if (bf) ((__hip_bfloat16*)outv)[off] = __float2bfloat16(vv);
        else    ((float*)outv)[off] = vv;
    }
}

// ---------------- launch ----------------
extern "C" void kernel_launch(void* const* d_in, const int* in_sizes, int n_in,
                              void* d_out, int out_size, void* d_ws, size_t ws_size,
                              hipStream_t stream) {
    const void* points = d_in[0];
    const void* voxels = d_in[1];
    const void* w_in   = d_in[2];
    const void* s_in   = d_in[3];
    const void* t_in   = d_in[4];
    const int* coors = (const int*)d_in[35];
    const int* p2v   = (const int*)d_in[36];

    char* ws = (char*)d_ws;
    __hip_bfloat16* wf   = (__hip_bfloat16*)(ws + 0);
    float*          bn   = (float*)(ws + 1835008);
    __hip_bfloat16* hbuf = (__hip_bfloat16*)(ws + 4194304);    // 40001*32 bf16
    int*   idxmap = (int*)(ws + 8388608);                      // 4 MiB
    __hip_bfloat16* xP0A = (__hip_bfloat16*)(ws + 12582912);
    __hip_bfloat16* xP0B = (__hip_bfloat16*)(ws + 23398912);
    __hip_bfloat16* xP1A = (__hip_bfloat16*)(ws + 34214912);
    __hip_bfloat16* xP1B = (__hip_bfloat16*)(ws + 37560320);
    __hip_bfloat16* xP2A = (__hip_bfloat16*)(ws + 40905728);
    __hip_bfloat16* xP2B = (__hip_bfloat16*)(ws + 41497600);
    float* occ1 = (float*)(ws + 42089472);
    float* occ2 = (float*)(ws + 42613760);
    float* occ3 = (float*)(ws + 42679296);
    float* occ4 = (float*)(ws + 42687488);
    int*   cnt  = (int*)(ws + 42695680);
    int*   list = (int*)(ws + 43015680);                       // 3.2 MB
    int*   slotbuf = (int*)(ws + 46215680);                    // 800 KB
    int*   flag = (int*)(ws + 47015680);
    float* hbuf5 = (float*)(ws + 50331648);                    // 40000*20*32 f32 = 102.4 MB

    (void)hipMemsetAsync(idxmap, 0xFF, 4194304, stream);
    (void)hipMemsetAsync(cnt, 0, 160000, stream);
    (void)hipMemsetAsync(hbuf, 0, 2560064, stream);
    (void)hipMemsetAsync(xP0A, 0, 29506560, stream);   // all six activation buffers

    detect_dtype<<<1, 64, 0, stream>>>(points, flag);

    static const int widx[30] = {5,6,7, 8,9,10, 11,12,13, 14,15,16, 17,18,19,
                                 20,21,22, 23,24,25, 26,27,28, 29,30,31, 32,33,34};
    static const int wnn[30]  = {27648,32,32, 27648,32,32, 27648,32,32,
                                 55296,64,64, 110592,64,64, 110592,64,64,
                                 110592,64,64, 110592,64,64, 110592,64,64,
                                 221184,128,128};
    static const int woff[30] = {0,0,32, 27648,64,96, 55296,128,160,
                                 82944,192,256, 138240,320,384, 248832,448,512,
                                 359424,576,640, 470016,704,768, 580608,832,896,
                                 691200,960,1088};
    static const int wcin[30]  = {32,0,0, 32,0,0, 32,0,0, 32,0,0, 64,0,0,
                                  64,0,0, 64,0,0, 64,0,0, 64,0,0, 64,0,0};
    static const int wcout[30] = {32,0,0, 32,0,0, 32,0,0, 64,0,0, 64,0,0,
                                  64,0,0, 64,0,0, 64,0,0, 64,0,0, 128,0,0};
    CvtArgs ca;
    for (int i = 0; i < 30; ++i)
        ca.d[i] = CvtDesc{ d_in[widx[i]], wnn[i], woff[i], wcin[i], wcout[i] };
    cvt_weights<<<dim3(864, 30), 256, 0, stream>>>(ca, wf, bn, flag);

    build_lists<<<782, 256, 0, stream>>>(p2v, cnt, list, 200000);
    scatter_rank<<<157, 256, 0, stream>>>(coors, idxmap, cnt, list, slotbuf);
    vfe_points<<<782, 256, 0, stream>>>(points, voxels, w_in, s_in, t_in,
                                        p2v, cnt, slotbuf, hbuf5, flag);
    vfe_reduce<<<625, 256, 0, stream>>>(hbuf5, cnt, hbuf);

    // stage 0: -> (8,128,128) x32
    pool_occ0<<<512, 256, 0, stream>>>(idxmap, occ1);
    conv0_mfma<<<2048, 256, 0, stream>>>(hbuf, idxmap, xP0A, wf + 0, bn + 0, occ1);
    conv_mfma<32, 32, 1, 2><<<2048, 256, 0, stream>>>(
        xP0A, xP0B, wf + 27648, bn + 64, occ1, 130, 130, 8, 128, 128, 130, 130);
    conv_mfma<32, 32, 1, 2><<<2048, 256, 0, stream>>>(
        xP0B, xP0A, wf + 55296, bn + 128, occ1, 130, 130, 8, 128, 128, 130, 130);

    // stage 1: -> (4,64,64) x64
    pool_occ<<<64, 256, 0, stream>>>(occ1, occ2, 8, 128, 128, 4, 64, 64, 2);
    conv_mfma<32, 64, 2, 1><<<1024, 256, 0, stream>>>(
        xP0A, xP1A, wf + 82944, bn + 192, occ2, 130, 130, 4, 64, 64, 66, 66);
    conv_mfma<64, 64, 1, 1><<<1024, 256, 0, stream>>>(
        xP1A, xP1B, wf + 138240, bn + 320, occ2, 66, 66, 4, 64, 64, 66, 66);
    conv_mfma<64, 64, 1, 1><<<1024, 256, 0, stream>>>(
        xP1B, xP1A, wf + 248832, bn + 448, occ2, 66, 66, 4, 64, 64, 66, 66);

    // stage 2: -> (2,32,32) x64
    pool_occ<<<8, 256, 0, stream>>>(occ2, occ3, 4, 64, 64, 2, 32, 32, 2);
    conv_mfma<64, 64, 2, 1><<<128, 256, 0, stream>>>(
        xP1A, xP2A, wf + 359424, bn + 576, occ3, 66, 66, 2, 32, 32, 34, 34);
    conv_mfma<64, 64, 1, 1><<<128, 256, 0, stream>>>(
        xP2A, xP2B, wf + 470016, bn + 704, occ3, 34, 34, 2, 32, 32, 34, 34);
    conv_mfma<64, 64, 1, 1><<<128, 256, 0, stream>>>(
        xP2B, xP2A, wf + 580608, bn + 832, occ3, 34, 34, 2, 32, 32, 34, 34);

    // final: -> (128,2,32,32)
    pool_occ<<<8, 256, 0, stream>>>(occ3, occ4, 2, 32, 32, 2, 32, 32, 1);
    conv_out_mfma<<<256, 256, 0, stream>>>(xP2A, d_out, wf + 691200, bn + 960, occ4, flag);
}

// Round 11
// 379.034 us; speedup vs baseline: 1.2448x; 1.1163x over previous
//
#include <hip/hip_runtime.h>
#include <hip/hip_bf16.h>

#define DEV __device__ __forceinline__

typedef __bf16 bf16x8 __attribute__((ext_vector_type(8)));
typedef float f32x4 __attribute__((ext_vector_type(4)));

DEV float ldflex(const void* p, long i, int bf) {
    return bf ? __bfloat162float(((const __hip_bfloat16*)p)[i]) : ((const float*)p)[i];
}
DEV bf16x8 ldfrag(const __hip_bfloat16* p) { return *(const bf16x8*)(const void*)p; }

// ---------------- dtype probe ----------------
__global__ void detect_dtype(const void* probe, int* flag) {
    if (blockIdx.x == 0 && threadIdx.x == 0) {
        const unsigned short* u = (const unsigned short*)probe;
        int sane = 0;
        for (int i = 0; i < 256; ++i) {
            unsigned short v = u[i];
            int e = (v >> 7) & 0xFF;
            if (v == 0 || (e >= 107 && e <= 147)) sane++;
        }
        *flag = (sane >= 192) ? 1 : 0;   // 1 = bf16 storage
    }
}

// ---------------- weight conversion into MFMA B-fragment order ----------------
struct CvtDesc { const void* src; int n; int off; int cin; int cout; };
struct CvtArgs { CvtDesc d[30]; };

__global__ void cvt_weights(CvtArgs a, __hip_bfloat16* __restrict__ wf,
                            float* __restrict__ bn, const int* __restrict__ flagp) {
    CvtDesc de = a.d[blockIdx.y];
    int i = blockIdx.x * 256 + threadIdx.x;
    if (i >= de.n) return;
    float v = ldflex(de.src, i, *flagp);
    if (de.cin == 0) { bn[de.off + i] = v; return; }
    int cin = de.cin;
    int KB = cin >> 5, NH = de.cout >> 4;
    int co = i / (cin * 27);
    int rem = i % (cin * 27);
    int ci = rem / 27, tap = rem % 27;
    int kb = ci >> 5, q = (ci >> 3) & 3, j = ci & 7;
    int half = co >> 4, n = co & 15, lane = q * 16 + n;
    (void)KB;
    wf[de.off + ((((tap * KB + kb) * NH + half) << 9) + lane * 8 + j)] = __float2bfloat16(v);
}

// ---------------- point lists ----------------
__global__ void build_lists(const int* __restrict__ p2v, int* __restrict__ cnt,
                            int* __restrict__ list, int n) {
    int i = blockIdx.x * blockDim.x + threadIdx.x;
    if (i >= n) return;
    int v = p2v[i];
    int slot = atomicAdd(&cnt[v], 1);
    if (slot < 20) list[v * 20 + slot] = i;
}

// scatter voxel->grid index + assign deterministic slot ranks (sorted point order)
__global__ void scatter_rank(const int* __restrict__ coors, int* __restrict__ idxmap,
                             const int* __restrict__ cnt, const int* __restrict__ list,
                             int* __restrict__ slotbuf) {
    int v = blockIdx.x * blockDim.x + threadIdx.x;
    if (v >= 40000) return;
    int x = coors[v * 4 + 1], y = coors[v * 4 + 2], z = coors[v * 4 + 3];
    idxmap[((size_t)z * 256 + y) * 256 + x] = v;
    int c_ = min(cnt[v], 20);
    int idxs[20];
    for (int k = 0; k < c_; ++k) idxs[k] = list[v * 20 + k];
    for (int i = 1; i < c_; ++i) {
        int key = idxs[i]; int j = i - 1;
        while (j >= 0 && idxs[j] > key) { idxs[j + 1] = idxs[j]; --j; }
        idxs[j + 1] = key;
    }
    for (int k = 0; k < c_; ++k) slotbuf[idxs[k]] = k;   // rank in ascending-index order
}

// ---------------- VFE pass 1: point-major, coalesced reads, per-slot contributions ------
__global__ __launch_bounds__(256) void vfe_points(
    const void* __restrict__ points, const void* __restrict__ voxels,
    const void* __restrict__ w_in, const void* __restrict__ s_in, const void* __restrict__ t_in,
    const int* __restrict__ p2v, const int* __restrict__ cnt,
    const int* __restrict__ slotbuf, float* __restrict__ hbuf5,
    const int* __restrict__ flagp) {
    const int N = 200000, S = 20;
    __shared__ float lw[256], lsc[32], lbi[32];
    int bf = *flagp;
    if (threadIdx.x < 256) lw[threadIdx.x] = ldflex(w_in, threadIdx.x, bf);
    if (threadIdx.x < 32) {
        lsc[threadIdx.x] = ldflex(s_in, threadIdx.x, bf);
        lbi[threadIdx.x] = ldflex(t_in, threadIdx.x, bf);
    }
    __syncthreads();
    int i = blockIdx.x * 256 + threadIdx.x;
    if (i >= N) return;
    int slot = slotbuf[i];
    if (slot >= S) return;
    int v = p2v[i];
    float p0 = ldflex(points, i, bf);
    float p1 = ldflex(points, N + i, bf);
    float p2 = ldflex(points, 2 * N + i, bf);
    float p3 = ldflex(points, 3 * N + i, bf);
    float f0 = ldflex(voxels, v * 4 + 0, bf) - p0;
    float f1 = ldflex(voxels, v * 4 + 1, bf) - p1;
    float f2 = ldflex(voxels, v * 4 + 2, bf) - p2;
    float f3 = ldflex(voxels, v * 4 + 3, bf) - p3;
    int c_ = min(cnt[v], S);
    float mult = (slot == 0) ? (float)(S - c_ + 1) : 1.f;   // ref pads with first point
    float* out = hbuf5 + ((size_t)v * S + slot) * 32;
#pragma unroll
    for (int o = 0; o < 32; ++o) {
        float d = f0 * lw[o * 8 + 0] + f1 * lw[o * 8 + 1] + f2 * lw[o * 8 + 2] +
                  f3 * lw[o * 8 + 3] + p0 * lw[o * 8 + 4] + p1 * lw[o * 8 + 5] +
                  p2 * lw[o * 8 + 6] + p3 * lw[o * 8 + 7];
        out[o] = fmaxf(d * lsc[o] + lbi[o], 0.f) * mult;
    }
}

// ---------------- VFE pass 2: deterministic slot-order reduce -> bf16 h[v][32] ---------
__global__ __launch_bounds__(256) void vfe_reduce(
    const float* __restrict__ hbuf5, const int* __restrict__ cnt,
    __hip_bfloat16* __restrict__ hbuf) {
    int t = blockIdx.x * 256 + threadIdx.x;
    if (t >= 160000) return;
    int v = t >> 2, g = t & 3;
    int c_ = min(cnt[v], 20);
    f32x4 s0 = {0, 0, 0, 0}, s1 = {0, 0, 0, 0};
    const float* base = hbuf5 + (size_t)v * 20 * 32 + g * 8;
    for (int s = 0; s < c_; ++s) {          // ascending slot = ascending point index
        const f32x4* p = (const f32x4*)(base + s * 32);
        s0 += p[0]; s1 += p[1];
    }
    __hip_bfloat16* o = hbuf + (size_t)v * 32 + g * 8;
#pragma unroll
    for (int j = 0; j < 4; ++j) {
        o[j] = __float2bfloat16(s0[j] * 0.05f);
        o[4 + j] = __float2bfloat16(s1[j] * 0.05f);
    }
}

// ---------------- occupancy pools ----------------
__global__ void pool_occ0(const int* __restrict__ idxmap, float* __restrict__ out) {
    int idx = blockIdx.x * blockDim.x + threadIdx.x;
    if (idx >= 8 * 128 * 128) return;
    int w = idx % 128; int r = idx / 128;
    int h = r % 128;   int d = r / 128;
    float m = 0.f;
    for (int kd = 0; kd < 3; ++kd) {
        int id = d * 2 + kd - 1;
        if (id < 0 || id >= 16) continue;
        for (int kh = 0; kh < 3; ++kh) {
            int ih = h * 2 + kh - 1;
            if (ih < 0 || ih >= 256) continue;
            for (int kw = 0; kw < 3; ++kw) {
                int iw = w * 2 + kw - 1;
                if (iw < 0 || iw >= 256) continue;
                if (idxmap[((size_t)id * 256 + ih) * 256 + iw] >= 0) m = 1.f;
            }
        }
    }
    out[idx] = m;
}

__global__ void pool_occ(const float* __restrict__ in, float* __restrict__ out,
                         int Di, int Hi, int Wi, int Do, int Ho, int Wo, int stride) {
    int idx = blockIdx.x * blockDim.x + threadIdx.x;
    int total = Do * Ho * Wo;
    if (idx >= total) return;
    int w = idx % Wo; int r = idx / Wo;
    int h = r % Ho;   int d = r / Ho;
    float m = 0.f;
    for (int kd = 0; kd < 3; ++kd) {
        int id = d * stride + kd - 1;
        if (id < 0 || id >= Di) continue;
        for (int kh = 0; kh < 3; ++kh) {
            int ih = h * stride + kh - 1;
            if (ih < 0 || ih >= Hi) continue;
            for (int kw = 0; kw < 3; ++kw) {
                int iw = w * stride + kw - 1;
                if (iw < 0 || iw >= Wi) continue;
                m = fmaxf(m, in[((size_t)id * Hi + ih) * Wi + iw]);
            }
        }
    }
    out[idx] = m;
}

// ---------------- conv0: sparse gather implicit-GEMM MFMA, 2 tiles/wave ----------------
__global__ __launch_bounds__(256) void conv0_mfma(
    const __hip_bfloat16* __restrict__ hb, const int* __restrict__ idxmap,
    __hip_bfloat16* __restrict__ out,                 // padded (10,130,130,32)
    const __hip_bfloat16* __restrict__ wf, const float* __restrict__ bns,
    const float* __restrict__ occ) {
    int wave = (blockIdx.x * 256 + threadIdx.x) >> 6;  // 4096 waves (tile-pairs)
    int lane = threadIdx.x & 63;
    int twg = wave & 3; int r = wave >> 2;             // 4 pairs across W
    int h = r & 127;    int d = r >> 7;
    int w0 = twg * 32;
    int q = lane >> 4, n = lane & 15;

    f32x4 acc[2][2];
#pragma unroll
    for (int t = 0; t < 2; ++t)
#pragma unroll
        for (int i = 0; i < 2; ++i) acc[t][i] = (f32x4){0.f, 0.f, 0.f, 0.f};

    const float* op = occ + ((size_t)(d * 128 + h)) * 128 + w0;
    bool any = (op[n] != 0.f) || (op[16 + n] != 0.f);
    if (__ballot(any)) {
#pragma unroll
        for (int kd = 0; kd < 3; ++kd) {
            int id = d * 2 + kd - 1;
            if (id < 0) continue;
#pragma unroll
            for (int kh = 0; kh < 3; ++kh) {
                int ih = h * 2 + kh - 1;
                if (ih < 0) continue;
                const int* ip = idxmap + ((size_t)id * 256 + ih) * 256;
#pragma unroll
                for (int kw = 0; kw < 3; ++kw) {
                    int tap = (kd * 3 + kh) * 3 + kw;
                    bf16x8 A[2];
#pragma unroll
                    for (int t = 0; t < 2; ++t) {
                        int iw = (w0 + t * 16 + n) * 2 + kw - 1;
                        int v = (iw >= 0) ? ip[iw] : -1;
                        int vv = (v >= 0) ? v : 40000;          // row 40000 = zeros
                        A[t] = ldfrag(hb + (size_t)vv * 32 + q * 8);
                    }
#pragma unroll
                    for (int i = 0; i < 2; ++i) {
                        bf16x8 B = ldfrag(wf + ((tap * 2 + i) << 9) + lane * 8);
#pragma unroll
                        for (int t = 0; t < 2; ++t)
                            acc[t][i] = __builtin_amdgcn_mfma_f32_16x16x32_bf16(
                                A[t], B, acc[t][i], 0, 0, 0);
                    }
                }
            }
        }
    }
#pragma unroll
    for (int t = 0; t < 2; ++t)
#pragma unroll
        for (int half = 0; half < 2; ++half) {
            int co = half * 16 + n;
            float s = bns[co], b = bns[32 + co];
#pragma unroll
            for (int r2 = 0; r2 < 4; ++r2) {
                int mm = t * 16 + q * 4 + r2;
                float oc = op[mm];
                float vv = fmaxf(acc[t][half][r2] * s + b, 0.f) * oc;
                out[((size_t)((d + 1) * 130 + (h + 1)) * 130 + (w0 + mm + 1)) * 32 + co] =
                    __float2bfloat16(vv);
            }
        }
}

// ---------------- dense implicit-GEMM MFMA conv: TILES spatial tiles, NHP halves/wave ----
template <int CIN, int COUT, int STRIDE, int NHP, int TILES>
__global__ __launch_bounds__(256) void conv_mfma(
    const __hip_bfloat16* __restrict__ in, __hip_bfloat16* __restrict__ out,
    const __hip_bfloat16* __restrict__ wf, const float* __restrict__ bns,
    const float* __restrict__ occ,
    int Hp, int Wp, int Do, int Ho, int Wo, int OHp, int OWp) {
    constexpr int KB = CIN / 32, NH = COUT / 16, NG = NH / NHP;
    int gw = (blockIdx.x * 256 + threadIdx.x) >> 6;
    int lane = threadIdx.x & 63;
    int hg = gw % NG;
    int wave = gw / NG;
    int ngw = (Wo >> 4) / TILES;
    int twg = wave % ngw; int r = wave / ngw;
    int h = r % Ho; int d = r / Ho;
    int w0 = twg * TILES * 16;
    int q = lane >> 4, n = lane & 15;

    f32x4 acc[TILES][NHP];
#pragma unroll
    for (int t = 0; t < TILES; ++t)
#pragma unroll
        for (int i = 0; i < NHP; ++i) acc[t][i] = (f32x4){0.f, 0.f, 0.f, 0.f};

    const float* op = occ + ((size_t)(d * Ho + h)) * Wo + w0;
    bool any = false;
#pragma unroll
    for (int t = 0; t < TILES; ++t) any = any || (op[t * 16 + n] != 0.f);
    if (__ballot(any)) {
#pragma unroll
        for (int kd = 0; kd < 3; ++kd) {
#pragma unroll
            for (int kh = 0; kh < 3; ++kh) {
#pragma unroll
                for (int kw = 0; kw < 3; ++kw) {
                    int tap = (kd * 3 + kh) * 3 + kw;
                    const __hip_bfloat16* ip = in +
                        ((size_t)((d * STRIDE + kd) * Hp + (h * STRIDE + kh)) * Wp +
                         (w0 * STRIDE + kw)) * CIN;
#pragma unroll
                    for (int kb = 0; kb < KB; ++kb) {
                        bf16x8 A[TILES];
#pragma unroll
                        for (int t = 0; t < TILES; ++t)
                            A[t] = ldfrag(ip + ((t * 16 + n) * STRIDE) * CIN + kb * 32 + q * 8);
#pragma unroll
                        for (int i = 0; i < NHP; ++i) {
                            int half = hg * NHP + i;
                            bf16x8 B = ldfrag(
                                wf + (((tap * KB + kb) * NH + half) << 9) + lane * 8);
#pragma unroll
                            for (int t = 0; t < TILES; ++t)
                                acc[t][i] = __builtin_amdgcn_mfma_f32_16x16x32_bf16(
                                    A[t], B, acc[t][i], 0, 0, 0);
                        }
                    }
                }
            }
        }
    }
#pragma unroll
    for (int t = 0; t < TILES; ++t)
#pragma unroll
        for (int i = 0; i < NHP; ++i) {
            int co = (hg * NHP + i) * 16 + n;
            float s = bns[co], b = bns[COUT + co];
#pragma unroll
            for (int r2 = 0; r2 < 4; ++r2) {
                int mm = t * 16 + q * 4 + r2;
                float oc = op[mm];
                float vv = fmaxf(acc[t][i][r2] * s + b, 0.f) * oc;
                out[((size_t)((d + 1) * OHp + (h + 1)) * OWp + (w0 + mm + 1)) * COUT + co] =
                    __float2bfloat16(vv);
            }
        }
}

// ---------------- final conv 64->128, NCDHW typed output ----------------
__global__ __launch_bounds__(256) void conv_out_mfma(
    const __hip_bfloat16* __restrict__ in,            // padded (4,34,34,64)
    void* __restrict__ outv,
    const __hip_bfloat16* __restrict__ wf, const float* __restrict__ bns,
    const float* __restrict__ occ, const int* __restrict__ flagp) {
    constexpr int KB = 2, NH = 8;
    int gw = (blockIdx.x * 256 + threadIdx.x) >> 6;   // 1024 waves
    int lane = threadIdx.x & 63;
    int hg = gw & 7;
    int wave = gw >> 3;
    int tw = wave & 1; int r = wave >> 1;
    int h = r & 31;    int d = r >> 5;
    int w0 = tw * 16;
    int q = lane >> 4, n = lane & 15;

    f32x4 acc = {0.f, 0.f, 0.f, 0.f};
    const float* op = occ + ((size_t)(d * 32 + h)) * 32 + w0;
    float ocn = op[n];
    if (__ballot(ocn != 0.f)) {
#pragma unroll
        for (int kd = 0; kd < 3; ++kd) {
#pragma unroll
            for (int kh = 0; kh < 3; ++kh) {
#pragma unroll
                for (int kw = 0; kw < 3; ++kw) {
                    int tap = (kd * 3 + kh) * 3 + kw;
                    const __hip_bfloat16* ip = in +
                        ((size_t)((d + kd) * 34 + (h + kh)) * 34 + (w0 + kw)) * 64;
#pragma unroll
                    for (int kb = 0; kb < KB; ++kb) {
                        bf16x8 A = ldfrag(ip + n * 64 + kb * 32 + q * 8);
                        acc = __builtin_amdgcn_mfma_f32_16x16x32_bf16(
                            A, ldfrag(wf + (((tap * KB + kb) * NH + hg) << 9) + lane * 8),
                            acc, 0, 0, 0);
                    }
                }
            }
        }
    }
    int bf = *flagp;
    int co = hg * 16 + n;
    float s = bns[co], b = bns[128 + co];
#pragma unroll
    for (int r2 = 0; r2 < 4; ++r2) {
        int mm = q * 4 + r2;
        float oc = op[mm];
        float vv = fmaxf(acc[r2] * s + b, 0.f) * oc;
        size_t off = (size_t)co * 2048 + ((size_t)(d * 32 + h)) * 32 + (w0 + mm);
        if (bf) ((__hip_bfloat16*)outv)[off] = __float2bfloat16(vv);
        else    ((float*)outv)[off] = vv;
    }
}

// ---------------- launch ----------------
extern "C" void kernel_launch(void* const* d_in, const int* in_sizes, int n_in,
                              void* d_out, int out_size, void* d_ws, size_t ws_size,
                              hipStream_t stream) {
    const void* points = d_in[0];
    const void* voxels = d_in[1];
    const void* w_in   = d_in[2];
    const void* s_in   = d_in[3];
    const void* t_in   = d_in[4];
    const int* coors = (const int*)d_in[35];
    const int* p2v   = (const int*)d_in[36];

    char* ws = (char*)d_ws;
    __hip_bfloat16* wf   = (__hip_bfloat16*)(ws + 0);
    float*          bn   = (float*)(ws + 1835008);
    __hip_bfloat16* hbuf = (__hip_bfloat16*)(ws + 4194304);    // 40001*32 bf16
    int*   idxmap = (int*)(ws + 8388608);                      // 4 MiB
    __hip_bfloat16* xP0A = (__hip_bfloat16*)(ws + 12582912);
    __hip_bfloat16* xP0B = (__hip_bfloat16*)(ws + 23398912);
    __hip_bfloat16* xP1A = (__hip_bfloat16*)(ws + 34214912);
    __hip_bfloat16* xP1B = (__hip_bfloat16*)(ws + 37560320);
    __hip_bfloat16* xP2A = (__hip_bfloat16*)(ws + 40905728);
    __hip_bfloat16* xP2B = (__hip_bfloat16*)(ws + 41497600);
    float* occ1 = (float*)(ws + 42089472);
    float* occ2 = (float*)(ws + 42613760);
    float* occ3 = (float*)(ws + 42679296);
    float* occ4 = (float*)(ws + 42687488);
    int*   cnt  = (int*)(ws + 42695680);
    int*   list = (int*)(ws + 43015680);                       // 3.2 MB
    int*   slotbuf = (int*)(ws + 46215680);                    // 800 KB
    int*   flag = (int*)(ws + 47015680);
    float* hbuf5 = (float*)(ws + 50331648);                    // 40000*20*32 f32

    (void)hipMemsetAsync(idxmap, 0xFF, 4194304, stream);
    (void)hipMemsetAsync(cnt, 0, 160000, stream);
    (void)hipMemsetAsync(hbuf, 0, 2560064, stream);
    (void)hipMemsetAsync(xP0A, 0, 29506560, stream);   // all six activation buffers

    detect_dtype<<<1, 64, 0, stream>>>(points, flag);

    static const int widx[30] = {5,6,7, 8,9,10, 11,12,13, 14,15,16, 17,18,19,
                                 20,21,22, 23,24,25, 26,27,28, 29,30,31, 32,33,34};
    static const int wnn[30]  = {27648,32,32, 27648,32,32, 27648,32,32,
                                 55296,64,64, 110592,64,64, 110592,64,64,
                                 110592,64,64, 110592,64,64, 110592,64,64,
                                 221184,128,128};
    static const int woff[30] = {0,0,32, 27648,64,96, 55296,128,160,
                                 82944,192,256, 138240,320,384, 248832,448,512,
                                 359424,576,640, 470016,704,768, 580608,832,896,
                                 691200,960,1088};
    static const int wcin[30]  = {32,0,0, 32,0,0, 32,0,0, 32,0,0, 64,0,0,
                                  64,0,0, 64,0,0, 64,0,0, 64,0,0, 64,0,0};
    static const int wcout[30] = {32,0,0, 32,0,0, 32,0,0, 64,0,0, 64,0,0,
                                  64,0,0, 64,0,0, 64,0,0, 64,0,0, 128,0,0};
    CvtArgs ca;
    for (int i = 0; i < 30; ++i)
        ca.d[i] = CvtDesc{ d_in[widx[i]], wnn[i], woff[i], wcin[i], wcout[i] };
    cvt_weights<<<dim3(864, 30), 256, 0, stream>>>(ca, wf, bn, flag);

    build_lists<<<782, 256, 0, stream>>>(p2v, cnt, list, 200000);
    scatter_rank<<<157, 256, 0, stream>>>(coors, idxmap, cnt, list, slotbuf);
    vfe_points<<<782, 256, 0, stream>>>(points, voxels, w_in, s_in, t_in,
                                        p2v, cnt, slotbuf, hbuf5, flag);
    vfe_reduce<<<625, 256, 0, stream>>>(hbuf5, cnt, hbuf);

    // stage 0: -> (8,128,128) x32   (4096 tile-pair waves = 1024 blocks)
    pool_occ0<<<512, 256, 0, stream>>>(idxmap, occ1);
    conv0_mfma<<<1024, 256, 0, stream>>>(hbuf, idxmap, xP0A, wf + 0, bn + 0, occ1);
    conv_mfma<32, 32, 1, 2, 2><<<1024, 256, 0, stream>>>(
        xP0A, xP0B, wf + 27648, bn + 64, occ1, 130, 130, 8, 128, 128, 130, 130);
    conv_mfma<32, 32, 1, 2, 2><<<1024, 256, 0, stream>>>(
        xP0B, xP0A, wf + 55296, bn + 128, occ1, 130, 130, 8, 128, 128, 130, 130);

    // stage 1: -> (4,64,64) x64   (512 tile-pairs × 2 half-groups = 1024 waves)
    pool_occ<<<64, 256, 0, stream>>>(occ1, occ2, 8, 128, 128, 4, 64, 64, 2);
    conv_mfma<32, 64, 2, 2, 2><<<256, 256, 0, stream>>>(
        xP0A, xP1A, wf + 82944, bn + 192, occ2, 130, 130, 4, 64, 64, 66, 66);
    conv_mfma<64, 64, 1, 2, 2><<<256, 256, 0, stream>>>(
        xP1A, xP1B, wf + 138240, bn + 320, occ2, 66, 66, 4, 64, 64, 66, 66);
    conv_mfma<64, 64, 1, 2, 2><<<256, 256, 0, stream>>>(
        xP1B, xP1A, wf + 248832, bn + 448, occ2, 66, 66, 4, 64, 64, 66, 66);

    // stage 2: -> (2,32,32) x64   (128 tiles × 4 half-groups = 512 waves, unchanged)
    pool_occ<<<8, 256, 0, stream>>>(occ2, occ3, 4, 64, 64, 2, 32, 32, 2);
    conv_mfma<64, 64, 2, 1, 1><<<128, 256, 0, stream>>>(
        xP1A, xP2A, wf + 359424, bn + 576, occ3, 66, 66, 2, 32, 32, 34, 34);
    conv_mfma<64, 64, 1, 1, 1><<<128, 256, 0, stream>>>(
        xP2A, xP2B, wf + 470016, bn + 704, occ3, 34, 34, 2, 32, 32, 34, 34);
    conv_mfma<64, 64, 1, 1, 1><<<128, 256, 0, stream>>>(
        xP2B, xP2A, wf + 580608, bn + 832, occ3, 34, 34, 2, 32, 32, 34, 34);

    // final: -> (128,2,32,32)
    pool_occ<<<8, 256, 0, stream>>>(occ3, occ4, 2, 32, 32, 2, 32, 32, 1);
    conv_out_mfma<<<256, 256, 0, stream>>>(xP2A, d_out, wf + 691200, bn + 960, occ4, flag);
}

// Round 12
// 375.194 us; speedup vs baseline: 1.2576x; 1.0102x over previous
//
#include <hip/hip_runtime.h>
#include <hip/hip_bf16.h>

#define DEV __device__ __forceinline__

typedef __bf16 bf16x8 __attribute__((ext_vector_type(8)));
typedef float f32x4 __attribute__((ext_vector_type(4)));

DEV float ldflex(const void* p, long i, int bf) {
    return bf ? __bfloat162float(((const __hip_bfloat16*)p)[i]) : ((const float*)p)[i];
}
DEV bf16x8 ldfrag(const __hip_bfloat16* p) { return *(const bf16x8*)(const void*)p; }

// ---------------- dtype probe ----------------
__global__ void detect_dtype(const void* probe, int* flag) {
    if (blockIdx.x == 0 && threadIdx.x == 0) {
        const unsigned short* u = (const unsigned short*)probe;
        int sane = 0;
        for (int i = 0; i < 256; ++i) {
            unsigned short v = u[i];
            int e = (v >> 7) & 0xFF;
            if (v == 0 || (e >= 107 && e <= 147)) sane++;
        }
        *flag = (sane >= 192) ? 1 : 0;   // 1 = bf16 storage
    }
}

// ---------------- weight conversion into MFMA B-fragment order ----------------
struct CvtDesc { const void* src; int n; int off; int cin; int cout; };
struct CvtArgs { CvtDesc d[30]; };

__global__ void cvt_weights(CvtArgs a, __hip_bfloat16* __restrict__ wf,
                            float* __restrict__ bn, const int* __restrict__ flagp) {
    CvtDesc de = a.d[blockIdx.y];
    int i = blockIdx.x * 256 + threadIdx.x;
    if (i >= de.n) return;
    float v = ldflex(de.src, i, *flagp);
    if (de.cin == 0) { bn[de.off + i] = v; return; }
    int cin = de.cin;
    int KB = cin >> 5, NH = de.cout >> 4;
    int co = i / (cin * 27);
    int rem = i % (cin * 27);
    int ci = rem / 27, tap = rem % 27;
    int kb = ci >> 5, q = (ci >> 3) & 3, j = ci & 7;
    int half = co >> 4, n = co & 15, lane = q * 16 + n;
    (void)KB;
    wf[de.off + ((((tap * KB + kb) * NH + half) << 9) + lane * 8 + j)] = __float2bfloat16(v);
}

// ---------------- point lists ----------------
__global__ void build_lists(const int* __restrict__ p2v, int* __restrict__ cnt,
                            int* __restrict__ list, int n) {
    int i = blockIdx.x * blockDim.x + threadIdx.x;
    if (i >= n) return;
    int v = p2v[i];
    int slot = atomicAdd(&cnt[v], 1);
    if (slot < 20) list[v * 20 + slot] = i;
}

// scatter voxel->grid index + assign deterministic slot ranks (sorted point order)
__global__ void scatter_rank(const int* __restrict__ coors, int* __restrict__ idxmap,
                             const int* __restrict__ cnt, const int* __restrict__ list,
                             int* __restrict__ slotbuf) {
    int v = blockIdx.x * blockDim.x + threadIdx.x;
    if (v >= 40000) return;
    int x = coors[v * 4 + 1], y = coors[v * 4 + 2], z = coors[v * 4 + 3];
    idxmap[((size_t)z * 256 + y) * 256 + x] = v;
    int c_ = min(cnt[v], 20);
    int idxs[20];
    for (int k = 0; k < c_; ++k) idxs[k] = list[v * 20 + k];
    for (int i = 1; i < c_; ++i) {
        int key = idxs[i]; int j = i - 1;
        while (j >= 0 && idxs[j] > key) { idxs[j + 1] = idxs[j]; --j; }
        idxs[j + 1] = key;
    }
    for (int k = 0; k < c_; ++k) slotbuf[idxs[k]] = k;   // rank in ascending-index order
}

// ---------------- VFE pass 1: point-major, coalesced reads, per-slot contributions ------
__global__ __launch_bounds__(256) void vfe_points(
    const void* __restrict__ points, const void* __restrict__ voxels,
    const void* __restrict__ w_in, const void* __restrict__ s_in, const void* __restrict__ t_in,
    const int* __restrict__ p2v, const int* __restrict__ cnt,
    const int* __restrict__ slotbuf, float* __restrict__ hbuf5,
    const int* __restrict__ flagp) {
    const int N = 200000, S = 20;
    __shared__ float lw[256], lsc[32], lbi[32];
    int bf = *flagp;
    if (threadIdx.x < 256) lw[threadIdx.x] = ldflex(w_in, threadIdx.x, bf);
    if (threadIdx.x < 32) {
        lsc[threadIdx.x] = ldflex(s_in, threadIdx.x, bf);
        lbi[threadIdx.x] = ldflex(t_in, threadIdx.x, bf);
    }
    __syncthreads();
    int i = blockIdx.x * 256 + threadIdx.x;
    if (i >= N) return;
    int slot = slotbuf[i];
    if (slot >= S) return;
    int v = p2v[i];
    float p0 = ldflex(points, i, bf);
    float p1 = ldflex(points, N + i, bf);
    float p2 = ldflex(points, 2 * N + i, bf);
    float p3 = ldflex(points, 3 * N + i, bf);
    float f0 = ldflex(voxels, v * 4 + 0, bf) - p0;
    float f1 = ldflex(voxels, v * 4 + 1, bf) - p1;
    float f2 = ldflex(voxels, v * 4 + 2, bf) - p2;
    float f3 = ldflex(voxels, v * 4 + 3, bf) - p3;
    int c_ = min(cnt[v], S);
    float mult = (slot == 0) ? (float)(S - c_ + 1) : 1.f;   // ref pads with first point
    float* out = hbuf5 + ((size_t)v * S + slot) * 32;
#pragma unroll
    for (int o = 0; o < 32; ++o) {
        float d = f0 * lw[o * 8 + 0] + f1 * lw[o * 8 + 1] + f2 * lw[o * 8 + 2] +
                  f3 * lw[o * 8 + 3] + p0 * lw[o * 8 + 4] + p1 * lw[o * 8 + 5] +
                  p2 * lw[o * 8 + 6] + p3 * lw[o * 8 + 7];
        out[o] = fmaxf(d * lsc[o] + lbi[o], 0.f) * mult;
    }
}

// ---------------- VFE pass 2: deterministic slot-order reduce -> bf16 h[v][32] ---------
__global__ __launch_bounds__(256) void vfe_reduce(
    const float* __restrict__ hbuf5, const int* __restrict__ cnt,
    __hip_bfloat16* __restrict__ hbuf) {
    int t = blockIdx.x * 256 + threadIdx.x;
    if (t >= 160000) return;
    int v = t >> 2, g = t & 3;
    int c_ = min(cnt[v], 20);
    f32x4 s0 = {0, 0, 0, 0}, s1 = {0, 0, 0, 0};
    const float* base = hbuf5 + (size_t)v * 20 * 32 + g * 8;
    for (int s = 0; s < c_; ++s) {          // ascending slot = ascending point index
        const f32x4* p = (const f32x4*)(base + s * 32);
        s0 += p[0]; s1 += p[1];
    }
    __hip_bfloat16* o = hbuf + (size_t)v * 32 + g * 8;
#pragma unroll
    for (int j = 0; j < 4; ++j) {
        o[j] = __float2bfloat16(s0[j] * 0.05f);
        o[4 + j] = __float2bfloat16(s1[j] * 0.05f);
    }
}

// ---------------- occupancy pools ----------------
__global__ void pool_occ0(const int* __restrict__ idxmap, float* __restrict__ out) {
    int idx = blockIdx.x * blockDim.x + threadIdx.x;
    if (idx >= 8 * 128 * 128) return;
    int w = idx % 128; int r = idx / 128;
    int h = r % 128;   int d = r / 128;
    float m = 0.f;
    for (int kd = 0; kd < 3; ++kd) {
        int id = d * 2 + kd - 1;
        if (id < 0 || id >= 16) continue;
        for (int kh = 0; kh < 3; ++kh) {
            int ih = h * 2 + kh - 1;
            if (ih < 0 || ih >= 256) continue;
            for (int kw = 0; kw < 3; ++kw) {
                int iw = w * 2 + kw - 1;
                if (iw < 0 || iw >= 256) continue;
                if (idxmap[((size_t)id * 256 + ih) * 256 + iw] >= 0) m = 1.f;
            }
        }
    }
    out[idx] = m;
}

__global__ void pool_occ(const float* __restrict__ in, float* __restrict__ out,
                         int Di, int Hi, int Wi, int Do, int Ho, int Wo, int stride) {
    int idx = blockIdx.x * blockDim.x + threadIdx.x;
    int total = Do * Ho * Wo;
    if (idx >= total) return;
    int w = idx % Wo; int r = idx / Wo;
    int h = r % Ho;   int d = r / Ho;
    float m = 0.f;
    for (int kd = 0; kd < 3; ++kd) {
        int id = d * stride + kd - 1;
        if (id < 0 || id >= Di) continue;
        for (int kh = 0; kh < 3; ++kh) {
            int ih = h * stride + kh - 1;
            if (ih < 0 || ih >= Hi) continue;
            for (int kw = 0; kw < 3; ++kw) {
                int iw = w * stride + kw - 1;
                if (iw < 0 || iw >= Wi) continue;
                m = fmaxf(m, in[((size_t)id * Hi + ih) * Wi + iw]);
            }
        }
    }
    out[idx] = m;
}

// ---------------- conv0: sparse gather implicit-GEMM MFMA, 4 tiles/wave ----------------
__global__ __launch_bounds__(256) void conv0_mfma(
    const __hip_bfloat16* __restrict__ hb, const int* __restrict__ idxmap,
    __hip_bfloat16* __restrict__ out,                 // padded (10,130,130,32)
    const __hip_bfloat16* __restrict__ wf, const float* __restrict__ bns,
    const float* __restrict__ occ) {
    int wave = (blockIdx.x * 256 + threadIdx.x) >> 6;  // 2048 waves (4-tile groups)
    int lane = threadIdx.x & 63;
    int twg = wave & 1; int r = wave >> 1;             // 2 groups of 64 across W
    int h = r & 127;    int d = r >> 7;
    int w0 = twg * 64;
    int q = lane >> 4, n = lane & 15;

    f32x4 acc[4][2];
#pragma unroll
    for (int t = 0; t < 4; ++t)
#pragma unroll
        for (int i = 0; i < 2; ++i) acc[t][i] = (f32x4){0.f, 0.f, 0.f, 0.f};

    const float* op = occ + ((size_t)(d * 128 + h)) * 128 + w0;
    bool any = false;
#pragma unroll
    for (int t = 0; t < 4; ++t) any = any || (op[t * 16 + n] != 0.f);
    if (__ballot(any)) {
#pragma unroll
        for (int kd = 0; kd < 3; ++kd) {
            int id = d * 2 + kd - 1;
            if (id < 0) continue;
#pragma unroll
            for (int kh = 0; kh < 3; ++kh) {
                int ih = h * 2 + kh - 1;
                if (ih < 0) continue;
                const int* ip = idxmap + ((size_t)id * 256 + ih) * 256;
#pragma unroll
                for (int kw = 0; kw < 3; ++kw) {
                    int tap = (kd * 3 + kh) * 3 + kw;
                    bf16x8 A[4];
#pragma unroll
                    for (int t = 0; t < 4; ++t) {
                        int iw = (w0 + t * 16 + n) * 2 + kw - 1;
                        int v = (iw >= 0) ? ip[iw] : -1;
                        int vv = (v >= 0) ? v : 40000;          // row 40000 = zeros
                        A[t] = ldfrag(hb + (size_t)vv * 32 + q * 8);
                    }
#pragma unroll
                    for (int i = 0; i < 2; ++i) {
                        bf16x8 B = ldfrag(wf + ((tap * 2 + i) << 9) + lane * 8);
#pragma unroll
                        for (int t = 0; t < 4; ++t)
                            acc[t][i] = __builtin_amdgcn_mfma_f32_16x16x32_bf16(
                                A[t], B, acc[t][i], 0, 0, 0);
                    }
                }
            }
        }
    }
#pragma unroll
    for (int t = 0; t < 4; ++t)
#pragma unroll
        for (int half = 0; half < 2; ++half) {
            int co = half * 16 + n;
            float s = bns[co], b = bns[32 + co];
#pragma unroll
            for (int r2 = 0; r2 < 4; ++r2) {
                int mm = t * 16 + q * 4 + r2;
                float oc = op[mm];
                float vv = fmaxf(acc[t][half][r2] * s + b, 0.f) * oc;
                out[((size_t)((d + 1) * 130 + (h + 1)) * 130 + (w0 + mm + 1)) * 32 + co] =
                    __float2bfloat16(vv);
            }
        }
}

// ---------------- dense implicit-GEMM MFMA conv: TILES spatial tiles, NHP halves/wave ----
template <int CIN, int COUT, int STRIDE, int NHP, int TILES>
__global__ __launch_bounds__(256) void conv_mfma(
    const __hip_bfloat16* __restrict__ in, __hip_bfloat16* __restrict__ out,
    const __hip_bfloat16* __restrict__ wf, const float* __restrict__ bns,
    const float* __restrict__ occ,
    int Hp, int Wp, int Do, int Ho, int Wo, int OHp, int OWp) {
    constexpr int KB = CIN / 32, NH = COUT / 16, NG = NH / NHP;
    int gw = (blockIdx.x * 256 + threadIdx.x) >> 6;
    int lane = threadIdx.x & 63;
    int hg = gw % NG;
    int wave = gw / NG;
    int ngw = (Wo >> 4) / TILES;
    int twg = wave % ngw; int r = wave / ngw;
    int h = r % Ho; int d = r / Ho;
    int w0 = twg * TILES * 16;
    int q = lane >> 4, n = lane & 15;

    f32x4 acc[TILES][NHP];
#pragma unroll
    for (int t = 0; t < TILES; ++t)
#pragma unroll
        for (int i = 0; i < NHP; ++i) acc[t][i] = (f32x4){0.f, 0.f, 0.f, 0.f};

    const float* op = occ + ((size_t)(d * Ho + h)) * Wo + w0;
    bool any = false;
#pragma unroll
    for (int t = 0; t < TILES; ++t) any = any || (op[t * 16 + n] != 0.f);
    if (__ballot(any)) {
#pragma unroll
        for (int kd = 0; kd < 3; ++kd) {
#pragma unroll
            for (int kh = 0; kh < 3; ++kh) {
#pragma unroll
                for (int kw = 0; kw < 3; ++kw) {
                    int tap = (kd * 3 + kh) * 3 + kw;
                    const __hip_bfloat16* ip = in +
                        ((size_t)((d * STRIDE + kd) * Hp + (h * STRIDE + kh)) * Wp +
                         (w0 * STRIDE + kw)) * CIN;
#pragma unroll
                    for (int kb = 0; kb < KB; ++kb) {
                        bf16x8 A[TILES];
#pragma unroll
                        for (int t = 0; t < TILES; ++t)
                            A[t] = ldfrag(ip + ((t * 16 + n) * STRIDE) * CIN + kb * 32 + q * 8);
#pragma unroll
                        for (int i = 0; i < NHP; ++i) {
                            int half = hg * NHP + i;
                            bf16x8 B = ldfrag(
                                wf + (((tap * KB + kb) * NH + half) << 9) + lane * 8);
#pragma unroll
                            for (int t = 0; t < TILES; ++t)
                                acc[t][i] = __builtin_amdgcn_mfma_f32_16x16x32_bf16(
                                    A[t], B, acc[t][i], 0, 0, 0);
                        }
                    }
                }
            }
        }
    }
#pragma unroll
    for (int t = 0; t < TILES; ++t)
#pragma unroll
        for (int i = 0; i < NHP; ++i) {
            int co = (hg * NHP + i) * 16 + n;
            float s = bns[co], b = bns[COUT + co];
#pragma unroll
            for (int r2 = 0; r2 < 4; ++r2) {
                int mm = t * 16 + q * 4 + r2;
                float oc = op[mm];
                float vv = fmaxf(acc[t][i][r2] * s + b, 0.f) * oc;
                out[((size_t)((d + 1) * OHp + (h + 1)) * OWp + (w0 + mm + 1)) * COUT + co] =
                    __float2bfloat16(vv);
            }
        }
}

// ---------------- final conv 64->128, NCDHW typed output ----------------
__global__ __launch_bounds__(256) void conv_out_mfma(
    const __hip_bfloat16* __restrict__ in,            // padded (4,34,34,64)
    void* __restrict__ outv,
    const __hip_bfloat16* __restrict__ wf, const float* __restrict__ bns,
    const float* __restrict__ occ, const int* __restrict__ flagp) {
    constexpr int KB = 2, NH = 8;
    int gw = (blockIdx.x * 256 + threadIdx.x) >> 6;   // 1024 waves
    int lane = threadIdx.x & 63;
    int hg = gw & 7;
    int wave = gw >> 3;
    int tw = wave & 1; int r = wave >> 1;
    int h = r & 31;    int d = r >> 5;
    int w0 = tw * 16;
    int q = lane >> 4, n = lane & 15;

    f32x4 acc = {0.f, 0.f, 0.f, 0.f};
    const float* op = occ + ((size_t)(d * 32 + h)) * 32 + w0;
    float ocn = op[n];
    if (__ballot(ocn != 0.f)) {
#pragma unroll
        for (int kd = 0; kd < 3; ++kd) {
#pragma unroll
            for (int kh = 0; kh < 3; ++kh) {
#pragma unroll
                for (int kw = 0; kw < 3; ++kw) {
                    int tap = (kd * 3 + kh) * 3 + kw;
                    const __hip_bfloat16* ip = in +
                        ((size_t)((d + kd) * 34 + (h + kh)) * 34 + (w0 + kw)) * 64;
#pragma unroll
                    for (int kb = 0; kb < KB; ++kb) {
                        bf16x8 A = ldfrag(ip + n * 64 + kb * 32 + q * 8);
                        acc = __builtin_amdgcn_mfma_f32_16x16x32_bf16(
                            A, ldfrag(wf + (((tap * KB + kb) * NH + hg) << 9) + lane * 8),
                            acc, 0, 0, 0);
                    }
                }
            }
        }
    }
    int bf = *flagp;
    int co = hg * 16 + n;
    float s = bns[co], b = bns[128 + co];
#pragma unroll
    for (int r2 = 0; r2 < 4; ++r2) {
        int mm = q * 4 + r2;
        float oc = op[mm];
        float vv = fmaxf(acc[r2] * s + b, 0.f) * oc;
        size_t off = (size_t)co * 2048 + ((size_t)(d * 32 + h)) * 32 + (w0 + mm);
        if (bf) ((__hip_bfloat16*)outv)[off] = __float2bfloat16(vv);
        else    ((float*)outv)[off] = vv;
    }
}

// ---------------- launch ----------------
extern "C" void kernel_launch(void* const* d_in, const int* in_sizes, int n_in,
                              void* d_out, int out_size, void* d_ws, size_t ws_size,
                              hipStream_t stream) {
    const void* points = d_in[0];
    const void* voxels = d_in[1];
    const void* w_in   = d_in[2];
    const void* s_in   = d_in[3];
    const void* t_in   = d_in[4];
    const int* coors = (const int*)d_in[35];
    const int* p2v   = (const int*)d_in[36];

    char* ws = (char*)d_ws;
    __hip_bfloat16* wf   = (__hip_bfloat16*)(ws + 0);
    float*          bn   = (float*)(ws + 1835008);
    __hip_bfloat16* hbuf = (__hip_bfloat16*)(ws + 4194304);    // 40001*32 bf16
    int*   idxmap = (int*)(ws + 8388608);                      // 4 MiB
    __hip_bfloat16* xP0A = (__hip_bfloat16*)(ws + 12582912);
    __hip_bfloat16* xP0B = (__hip_bfloat16*)(ws + 23398912);
    __hip_bfloat16* xP1A = (__hip_bfloat16*)(ws + 34214912);
    __hip_bfloat16* xP1B = (__hip_bfloat16*)(ws + 37560320);
    __hip_bfloat16* xP2A = (__hip_bfloat16*)(ws + 40905728);
    __hip_bfloat16* xP2B = (__hip_bfloat16*)(ws + 41497600);
    float* occ1 = (float*)(ws + 42089472);
    float* occ2 = (float*)(ws + 42613760);
    float* occ3 = (float*)(ws + 42679296);
    float* occ4 = (float*)(ws + 42687488);
    int*   cnt  = (int*)(ws + 42695680);
    int*   list = (int*)(ws + 43015680);                       // 3.2 MB
    int*   slotbuf = (int*)(ws + 46215680);                    // 800 KB
    int*   flag = (int*)(ws + 47015680);
    float* hbuf5 = (float*)(ws + 50331648);                    // 40000*20*32 f32

    (void)hipMemsetAsync(idxmap, 0xFF, 4194304, stream);
    (void)hipMemsetAsync(cnt, 0, 160000, stream);
    (void)hipMemsetAsync(hbuf, 0, 2560064, stream);
    (void)hipMemsetAsync(xP0A, 0, 29506560, stream);   // all six activation buffers

    detect_dtype<<<1, 64, 0, stream>>>(points, flag);

    static const int widx[30] = {5,6,7, 8,9,10, 11,12,13, 14,15,16, 17,18,19,
                                 20,21,22, 23,24,25, 26,27,28, 29,30,31, 32,33,34};
    static const int wnn[30]  = {27648,32,32, 27648,32,32, 27648,32,32,
                                 55296,64,64, 110592,64,64, 110592,64,64,
                                 110592,64,64, 110592,64,64, 110592,64,64,
                                 221184,128,128};
    static const int woff[30] = {0,0,32, 27648,64,96, 55296,128,160,
                                 82944,192,256, 138240,320,384, 248832,448,512,
                                 359424,576,640, 470016,704,768, 580608,832,896,
                                 691200,960,1088};
    static const int wcin[30]  = {32,0,0, 32,0,0, 32,0,0, 32,0,0, 64,0,0,
                                  64,0,0, 64,0,0, 64,0,0, 64,0,0, 64,0,0};
    static const int wcout[30] = {32,0,0, 32,0,0, 32,0,0, 64,0,0, 64,0,0,
                                  64,0,0, 64,0,0, 64,0,0, 64,0,0, 128,0,0};
    CvtArgs ca;
    for (int i = 0; i < 30; ++i)
        ca.d[i] = CvtDesc{ d_in[widx[i]], wnn[i], woff[i], wcin[i], wcout[i] };
    cvt_weights<<<dim3(864, 30), 256, 0, stream>>>(ca, wf, bn, flag);

    build_lists<<<782, 256, 0, stream>>>(p2v, cnt, list, 200000);
    scatter_rank<<<157, 256, 0, stream>>>(coors, idxmap, cnt, list, slotbuf);
    vfe_points<<<782, 256, 0, stream>>>(points, voxels, w_in, s_in, t_in,
                                        p2v, cnt, slotbuf, hbuf5, flag);
    vfe_reduce<<<625, 256, 0, stream>>>(hbuf5, cnt, hbuf);

    // stage 0: -> (8,128,128) x32   (2048 4-tile waves = 512 blocks)
    pool_occ0<<<512, 256, 0, stream>>>(idxmap, occ1);
    conv0_mfma<<<512, 256, 0, stream>>>(hbuf, idxmap, xP0A, wf + 0, bn + 0, occ1);
    conv_mfma<32, 32, 1, 2, 4><<<512, 256, 0, stream>>>(
        xP0A, xP0B, wf + 27648, bn + 64, occ1, 130, 130, 8, 128, 128, 130, 130);
    conv_mfma<32, 32, 1, 2, 4><<<512, 256, 0, stream>>>(
        xP0B, xP0A, wf + 55296, bn + 128, occ1, 130, 130, 8, 128, 128, 130, 130);

    // stage 1: -> (4,64,64) x64   (512 tile-pairs × 2 half-groups = 1024 waves)
    pool_occ<<<64, 256, 0, stream>>>(occ1, occ2, 8, 128, 128, 4, 64, 64, 2);
    conv_mfma<32, 64, 2, 2, 2><<<256, 256, 0, stream>>>(
        xP0A, xP1A, wf + 82944, bn + 192, occ2, 130, 130, 4, 64, 64, 66, 66);
    conv_mfma<64, 64, 1, 2, 2><<<256, 256, 0, stream>>>(
        xP1A, xP1B, wf + 138240, bn + 320, occ2, 66, 66, 4, 64, 64, 66, 66);
    conv_mfma<64, 64, 1, 2, 2><<<256, 256, 0, stream>>>(
        xP1B, xP1A, wf + 248832, bn + 448, occ2, 66, 66, 4, 64, 64, 66, 66);

    // stage 2: -> (2,32,32) x64   (128 tiles × 4 half-groups = 512 waves)
    pool_occ<<<8, 256, 0, stream>>>(occ2, occ3, 4, 64, 64, 2, 32, 32, 2);
    conv_mfma<64, 64, 2, 1, 1><<<128, 256, 0, stream>>>(
        xP1A, xP2A, wf + 359424, bn + 576, occ3, 66, 66, 2, 32, 32, 34, 34);
    conv_mfma<64, 64, 1, 1, 1><<<128, 256, 0, stream>>>(
        xP2A, xP2B, wf + 470016, bn + 704, occ3, 34, 34, 2, 32, 32, 34, 34);
    conv_mfma<64, 64, 1, 1, 1><<<128, 256, 0, stream>>>(
        xP2B, xP2A, wf + 580608, bn + 832, occ3, 34, 34, 2, 32, 32, 34, 34);

    // final: -> (128,2,32,32)
    pool_occ<<<8, 256, 0, stream>>>(occ3, occ4, 2, 32, 32, 2, 32, 32, 1);
    conv_out_mfma<<<256, 256, 0, stream>>>(xP2A, d_out, wf + 691200, bn + 960, occ4, flag);
}